// Round 6
// baseline (1053.211 us; speedup 1.0000x reference)
//
#include <hip/hip_runtime.h>
#include <math.h>

#define Bn 32
#define Pn 256
#define Wn 16
#define Cn 64
#define Hn 128
#define PREDn 64
#define TOKn 17
#define TBLK 8

// ---------------- Kernel A1: logstd anchor partials (8 t-slices x 32 b) ----------------
__global__ void lsa_part_kernel(const float* __restrict__ std_hist,
                                float* __restrict__ lsa_part) {
  int b = blockIdx.x;
  int ts = blockIdx.y;               // 0..7 : 32-row slice of P
  int c = threadIdx.x & 63;
  int q = threadIdx.x >> 6;          // 0..3
  const float* base = std_hist + ((size_t)b * Pn + ts * 32) * Cn + c;
  float s = 0.f;
#pragma unroll
  for (int i = 0; i < 8; ++i) {
    int t = q + 4 * i;
    s += logf(fmaxf(base[(size_t)t * Cn], 1e-3f));
  }
  __shared__ float red[4][64];
  red[q][c] = s;
  __syncthreads();
  if (q == 0) {
    lsa_part[ts * 2048 + b * 64 + c] = red[0][c] + red[1][c] + red[2][c] + red[3][c];
  }
}

__global__ void lsa_combine_kernel(const float* __restrict__ lsa_part,
                                   float* __restrict__ lsa) {
  int i = blockIdx.x * 256 + threadIdx.x;  // 0..2047
  float v = 0.f;
#pragma unroll
  for (int k = 0; k < 8; ++k) v += lsa_part[k * 2048 + i];
  lsa[i] = v * (1.0f / 256.0f);
}

// ---------------- Kernel B: token matmul + EMA (hot kernel) ----------------
// NCH chunks of P (EMA linearity -> chunk results composed in head_kernel).
// block: 256 thr = 32 c x 64 hh for one (b, branch, chunk).
// Uncentered tokens (linearity; corrected in head_kernel).
// LDS row layout: words 0..15 = 16 raw features PERMUTED by rot=(c>>3)&3;
// word 16+rot = scalar feature. Wr pre-permuted to match -> natural-order
// b128 reads stay perfectly bank-tiled; writes/scalar spread across banks.
template <int NCH>
__launch_bounds__(256, 4)
__global__ void ema_kernel(
    const float* __restrict__ mu_hist, const float* __restrict__ std_hist,
    const float* __restrict__ raw,
    const float* __restrict__ mW, const float* __restrict__ mb, const float* __restrict__ mal,
    const float* __restrict__ sW, const float* __restrict__ sb, const float* __restrict__ sal,
    float* __restrict__ Spart) {
  constexpr int L = Pn / NCH;       // rows per chunk
  constexpr int NPH = L / TBLK;     // phases per chunk
  const int sx = blockIdx.x;        // 0..4*NCH-1
  const int cblk = sx & 1, hblk = (sx >> 1) & 1, ph = sx >> 2;
  const int b = blockIdx.y, br = blockIdx.z;
  const int tid = threadIdx.x;
  const int cr = tid & 31;
  const int w0 = tid >> 5;  // 0..7 : hh-group AND raw w-pair index

  const float* inW = br ? sW : mW;
  const float* inb = br ? sb : mb;
  const float* alog = br ? sal : mal;
  const int hh0 = hblk * 64 + w0 * 8;
  const int rot = (cr >> 3) & 3;

  // Wr[j] = W column for the feature stored at row word j (pre-permuted).
  float Wr[TOKn][8];
#pragma unroll
  for (int j = 0; j < 16; ++j) {
    int feat = 1 + 4 * (((j >> 2) + 4 - rot) & 3) + (j & 3);
    float4 wv0 = *(const float4*)&inW[feat * Hn + hh0];
    float4 wv1 = *(const float4*)&inW[feat * Hn + hh0 + 4];
    Wr[j][0] = wv0.x; Wr[j][1] = wv0.y; Wr[j][2] = wv0.z; Wr[j][3] = wv0.w;
    Wr[j][4] = wv1.x; Wr[j][5] = wv1.y; Wr[j][6] = wv1.z; Wr[j][7] = wv1.w;
  }
  {
    float4 wv0 = *(const float4*)&inW[hh0];
    float4 wv1 = *(const float4*)&inW[hh0 + 4];
    Wr[16][0] = wv0.x; Wr[16][1] = wv0.y; Wr[16][2] = wv0.z; Wr[16][3] = wv0.w;
    Wr[16][4] = wv1.x; Wr[16][5] = wv1.y; Wr[16][6] = wv1.z; Wr[16][7] = wv1.w;
  }
  float av[8], bias[8], h[8];
#pragma unroll
  for (int i = 0; i < 8; ++i) {
    av[i] = 1.0f / (1.0f + expf(-alog[hh0 + i]));
    bias[i] = inb[hh0 + i];
    h[i] = 0.0f;
  }

  const int cs = cblk * 32 + cr;
  const size_t bP = (size_t)b * Pn;
  const float* rawb = raw + bP * Wn * Cn;
  const float* mub = mu_hist + bP * Cn;
  const float* stdb = std_hist + bP * Cn;

  __shared__ float tok[2][TBLK][32 * 20];

  // write offsets for this thread's two raw features (g=w0 and g=w0+8)
  const int wf1 = cr * 20 + 4 * (((w0 >> 2) + rot) & 3) + (w0 & 3);
  const int wf2 = cr * 20 + 4 * ((((w0 + 8) >> 2) + rot) & 3) + (w0 & 3);
  // scalar-feature stager: all 256 threads cover TBLK x 32c
  const int cmu = tid & 31;
  const int tqmu = tid >> 5;  // 0..7
  const int wq_s = cmu * 20 + 16 + ((cmu >> 3) & 3);
  const int cmug = cblk * 32 + cmu;
  const int qo = cr * 20 + 16 + rot;

  const int t0 = ph * L;

  auto STAGE = [&](int tb, int buf) {
#pragma unroll
    for (int tq = 0; tq < TBLK; ++tq) {
      int t = tb + tq;
      const float* rawt = rawb + (size_t)t * (Wn * Cn);
      float r0 = rawt[w0 * Cn + cs];
      float r1 = rawt[(w0 + 8) * Cn + cs];
      if (br == 0) {
        tok[buf][tq][wf1] = r0;
        tok[buf][tq][wf2] = r1;
      } else {
        float mu = mub[(size_t)t * Cn + cs];
        float sd = stdb[(size_t)t * Cn + cs];
        float inv = 1.0f / (sd + 1e-5f);
        tok[buf][tq][wf1] = (r0 - mu) * inv;
        tok[buf][tq][wf2] = (r1 - mu) * inv;
      }
    }
    {
      int t = tb + tqmu;
      float v = br ? logf(fmaxf(stdb[(size_t)t * Cn + cmug], 1e-3f))
                   : mub[(size_t)t * Cn + cmug];
      tok[buf][tqmu][wq_s] = v;
    }
  };

  auto COMPUTE = [&](int buf) {
#pragma unroll
    for (int tq = 0; tq < TBLK; ++tq) {
      const float* row = &tok[buf][tq][cr * 20];
      float4 q0 = *(const float4*)(row);
      float4 q1 = *(const float4*)(row + 4);
      float4 q2 = *(const float4*)(row + 8);
      float4 q3 = *(const float4*)(row + 12);
      float q4 = tok[buf][tq][qo];
#pragma unroll
      for (int i = 0; i < 8; ++i) {
        float u = bias[i];
        u = fmaf(q0.x, Wr[0][i], u);
        u = fmaf(q0.y, Wr[1][i], u);
        u = fmaf(q0.z, Wr[2][i], u);
        u = fmaf(q0.w, Wr[3][i], u);
        u = fmaf(q1.x, Wr[4][i], u);
        u = fmaf(q1.y, Wr[5][i], u);
        u = fmaf(q1.z, Wr[6][i], u);
        u = fmaf(q1.w, Wr[7][i], u);
        u = fmaf(q2.x, Wr[8][i], u);
        u = fmaf(q2.y, Wr[9][i], u);
        u = fmaf(q2.z, Wr[10][i], u);
        u = fmaf(q2.w, Wr[11][i], u);
        u = fmaf(q3.x, Wr[12][i], u);
        u = fmaf(q3.y, Wr[13][i], u);
        u = fmaf(q3.z, Wr[14][i], u);
        u = fmaf(q3.w, Wr[15][i], u);
        u = fmaf(q4, Wr[16][i], u);
        h[i] = fmaf(av[i], h[i] - u, u);  // a*h + (1-a)*u
      }
    }
  };

  STAGE(t0, 0);
  __syncthreads();
  int cur = 0;
#pragma unroll 1
  for (int p = 0; p < NPH; ++p) {
    if (p + 1 < NPH) STAGE(t0 + (p + 1) * TBLK, cur ^ 1);
    COMPUTE(cur);
    __syncthreads();
    cur ^= 1;
  }

  // write chunk-EMA result (uncorrected), thread-contiguous
  const int idx_block = (((br * NCH + ph) * Bn + b) * 2 + cblk) * 2 + hblk;
  float* op = Spart + (size_t)idx_block * 2048 + tid * 8;
  float4 o0 = {h[0], h[1], h[2], h[3]};
  float4 o1 = {h[4], h[5], h[6], h[7]};
  *(float4*)op = o0;
  *(float4*)(op + 4) = o1;
}

// ---------------- Kernel C: combine chunks + centering correction + GELU-MLP head ----------------
// G (b,c) rows per block; NCH chunk composition h = sum_k aL^(NCH-1-k) * h_k.
template <int G, int NCH>
__launch_bounds__(128, 4)
__global__ void head_kernel(
    const float* __restrict__ anchor, const float* __restrict__ lsa,
    const float* __restrict__ mW, const float* __restrict__ sW,
    const float* __restrict__ mal, const float* __restrict__ mpW, const float* __restrict__ mpb,
    const float* __restrict__ moW, const float* __restrict__ mob, const float* __restrict__ gmu,
    const float* __restrict__ sal, const float* __restrict__ spW, const float* __restrict__ spb,
    const float* __restrict__ soW, const float* __restrict__ sob, const float* __restrict__ gst,
    const float* __restrict__ Spart, float* __restrict__ out) {
  constexpr int L = Pn / NCH;
  const int br = blockIdx.y;
  const int bc0 = blockIdx.x * G;  // G (b,c) rows per block
  const int tid = threadIdx.x;     // 0..127 = hh
  const float* alog = br ? sal : mal;
  const float* pW = br ? spW : mpW;
  const float* pb = br ? spb : mpb;
  const float* oW = br ? soW : moW;
  const float* ob = br ? sob : mob;

  __shared__ float smem[2 * G * 128];  // [0,G*128): gelu then reduce; [G*128,..): h2
  float* g_lds = smem;
  float* h2 = smem + G * 128;

  const float a = 1.0f / (1.0f + expf(-alog[tid]));
  float aL = a;  // a^L via log2(L) squarings
#pragma unroll
  for (int s7 = 0; s7 < 31 - __builtin_clz(L); ++s7) aL *= aL;
  float fac[NCH];
  fac[NCH - 1] = 1.0f;
#pragma unroll
  for (int k = NCH - 2; k >= 0; --k) fac[k] = fac[k + 1] * aL;
  const float apF = fac[0] * aL;  // a^Pn
  // centering correction: sum over shifted features of in_W column
  float SWv;
  if (br == 0) {
    float s = 0.f;
#pragma unroll
    for (int k = 0; k < TOKn; ++k) s += mW[k * Hn + tid];
    SWv = s;
  } else {
    SWv = sW[tid];  // only feature 0 (logstd) is shifted
  }
  const float cS = (1.0f - apF) * SWv;

  const int hblk = tid >> 6;
  const int hhg = (tid >> 3) & 7;
  const int ii = tid & 7;

  float hreg[G];
#pragma unroll
  for (int g = 0; g < G; ++g) {
    int bc = bc0 + g;
    int bb = bc >> 6, cc = bc & 63;
    int cblk2 = cc >> 5, crr = cc & 31;
    const size_t inner = (size_t)(hhg * 32 + crr) * 8 + ii;
    const int blk0 = (((br * NCH + 0) * Bn + bb) * 2 + cblk2) * 2 + hblk;
    float hv = 0.f;
#pragma unroll
    for (int k = 0; k < NCH; ++k) {
      hv = fmaf(fac[k], Spart[(size_t)(blk0 + k * (Bn * 4)) * 2048 + inner], hv);
    }
    float shiftv = br ? lsa[bb * Cn + cc] : anchor[bb * Cn + cc];
    hv = fmaf(-cS, shiftv, hv);  // centering correction
    hreg[g] = hv;
    g_lds[g * 128 + tid] = 0.5f * hv * (1.0f + erff(hv * 0.70710678118654752f));
  }
  __syncthreads();

  float acc[G];
#pragma unroll
  for (int g = 0; g < G; ++g) acc[g] = hreg[g] + pb[tid];
  for (int j = 0; j < 128; j += 4) {
    float w0v = pW[j * Hn + tid];
    float w1v = pW[(j + 1) * Hn + tid];
    float w2v = pW[(j + 2) * Hn + tid];
    float w3v = pW[(j + 3) * Hn + tid];
#pragma unroll
    for (int g = 0; g < G; ++g) {
      float4 gv = *(const float4*)&g_lds[g * 128 + j];
      acc[g] = fmaf(gv.x, w0v, acc[g]);
      acc[g] = fmaf(gv.y, w1v, acc[g]);
      acc[g] = fmaf(gv.z, w2v, acc[g]);
      acc[g] = fmaf(gv.w, w3v, acc[g]);
    }
  }
#pragma unroll
  for (int g = 0; g < G; ++g) h2[g * 128 + tid] = acc[g];
  __syncthreads();

  // out projection: p = tid&63, j-half = tid>>6
  const int p = tid & 63;
  const int jh = tid >> 6;
  float s[G];
#pragma unroll
  for (int g = 0; g < G; ++g) s[g] = 0.f;
  for (int jj = 0; jj < 64; jj += 4) {
    int j = jh * 64 + jj;
    float w0v = oW[j * PREDn + p];
    float w1v = oW[(j + 1) * PREDn + p];
    float w2v = oW[(j + 2) * PREDn + p];
    float w3v = oW[(j + 3) * PREDn + p];
#pragma unroll
    for (int g = 0; g < G; ++g) {
      float4 hv4 = *(const float4*)&h2[g * 128 + j];
      s[g] = fmaf(hv4.x, w0v, s[g]);
      s[g] = fmaf(hv4.y, w1v, s[g]);
      s[g] = fmaf(hv4.z, w2v, s[g]);
      s[g] = fmaf(hv4.w, w3v, s[g]);
    }
  }
  float* red = smem;  // reuse g_lds region (no longer read)
#pragma unroll
  for (int g = 0; g < G; ++g) red[jh * (G * 64) + g * 64 + p] = s[g];
  __syncthreads();
  if (tid < 64) {
#pragma unroll
    for (int g = 0; g < G; ++g) {
      int bc = bc0 + g;
      int bb = bc >> 6, cc = bc & 63;
      float tot = red[g * 64 + p] + red[G * 64 + g * 64 + p] + ob[p];
      if (br == 0) {
        out[((size_t)bb * PREDn + p) * Cn + cc] = fmaf(gmu[cc], tot, anchor[bb * Cn + cc]);
      } else {
        float lf = fmaf(gst[cc], tot, lsa[bb * Cn + cc]);
        out[131072 + ((size_t)bb * PREDn + p) * Cn + cc] = fmaxf(expf(lf), 1e-3f);
      }
    }
  }
}

extern "C" void kernel_launch(void* const* d_in, const int* in_sizes, int n_in,
                              void* d_out, int out_size, void* d_ws, size_t ws_size,
                              hipStream_t stream) {
  (void)in_sizes; (void)n_in; (void)out_size;
  const float* mu_hist = (const float*)d_in[0];
  const float* std_hist = (const float*)d_in[1];
  const float* anchor = (const float*)d_in[2];
  const float* raw = (const float*)d_in[3];
  const float* mW = (const float*)d_in[4];
  const float* mb_ = (const float*)d_in[5];
  const float* mal = (const float*)d_in[6];
  const float* mpW = (const float*)d_in[7];
  const float* mpb = (const float*)d_in[8];
  const float* moW = (const float*)d_in[9];
  const float* mob = (const float*)d_in[10];
  const float* gmu = (const float*)d_in[11];
  const float* sW = (const float*)d_in[12];
  const float* sb_ = (const float*)d_in[13];
  const float* sal = (const float*)d_in[14];
  const float* spW = (const float*)d_in[15];
  const float* spb = (const float*)d_in[16];
  const float* soW = (const float*)d_in[17];
  const float* sob = (const float*)d_in[18];
  const float* gst = (const float*)d_in[19];
  float* out = (float*)d_out;
  float* ws = (float*)d_ws;

  float* lsa = ws;                  // 2048 floats
  float* lsa_part = ws + 2048;      // 8*2048 floats
  float* Spart = ws + 2048 + 16384; // up to 256*NCH*2048 floats

  const size_t need4 = (size_t)(2048 + 16384 + 256 * 4 * 2048) * 4;

  hipLaunchKernelGGL(lsa_part_kernel, dim3(32, 8), dim3(256), 0, stream, std_hist, lsa_part);
  hipLaunchKernelGGL(lsa_combine_kernel, dim3(8), dim3(256), 0, stream, lsa_part, lsa);
  if (ws_size >= need4) {
    hipLaunchKernelGGL(HIP_KERNEL_NAME(ema_kernel<4>), dim3(16, 32, 2), dim3(256), 0, stream,
                       mu_hist, std_hist, raw, mW, mb_, mal, sW, sb_, sal, Spart);
    hipLaunchKernelGGL(HIP_KERNEL_NAME(head_kernel<2, 4>), dim3(1024, 2), dim3(128), 0, stream,
                       anchor, lsa, mW, sW, mal, mpW, mpb, moW, mob, gmu,
                       sal, spW, spb, soW, sob, gst, Spart, out);
  } else {
    hipLaunchKernelGGL(HIP_KERNEL_NAME(ema_kernel<2>), dim3(8, 32, 2), dim3(256), 0, stream,
                       mu_hist, std_hist, raw, mW, mb_, mal, sW, sb_, sal, Spart);
    hipLaunchKernelGGL(HIP_KERNEL_NAME(head_kernel<2, 2>), dim3(1024, 2), dim3(128), 0, stream,
                       anchor, lsa, mW, sW, mal, mpW, mpb, moW, mob, gmu,
                       sal, spW, spb, soW, sob, gst, Spart, out);
  }
}

// Round 7
// 212.435 us; speedup vs baseline: 4.9578x; 4.9578x over previous
//
#include <hip/hip_runtime.h>
#include <math.h>

#define Bn 32
#define Pn 256
#define Wn 16
#define Cn 64
#define Hn 128
#define PREDn 64
#define TOKn 17
#define TBLK 8

// ---------------- Kernel A1: logstd anchor partials (8 t-slices x 32 b) ----------------
__global__ void lsa_part_kernel(const float* __restrict__ std_hist,
                                float* __restrict__ lsa_part) {
  int b = blockIdx.x;
  int ts = blockIdx.y;               // 0..7 : 32-row slice of P
  int c = threadIdx.x & 63;
  int q = threadIdx.x >> 6;          // 0..3
  const float* base = std_hist + ((size_t)b * Pn + ts * 32) * Cn + c;
  float s = 0.f;
#pragma unroll
  for (int i = 0; i < 8; ++i) {
    int t = q + 4 * i;
    s += logf(fmaxf(base[(size_t)t * Cn], 1e-3f));
  }
  __shared__ float red[4][64];
  red[q][c] = s;
  __syncthreads();
  if (q == 0) {
    lsa_part[ts * 2048 + b * 64 + c] = red[0][c] + red[1][c] + red[2][c] + red[3][c];
  }
}

__global__ void lsa_combine_kernel(const float* __restrict__ lsa_part,
                                   float* __restrict__ lsa) {
  int i = blockIdx.x * 256 + threadIdx.x;  // 0..2047
  float v = 0.f;
#pragma unroll
  for (int k = 0; k < 8; ++k) v += lsa_part[k * 2048 + i];
  lsa[i] = v * (1.0f / 256.0f);
}

// ---------------- Kernel B: token matmul + EMA (hot kernel) ----------------
// NCH chunks of P (EMA linearity -> chunk results composed in head_kernel).
// block: 256 thr = 32 c x 64 hh for one (b, branch, chunk).
// Uncentered tokens (linearity; corrected in head_kernel).
// LDS row layout: words 0..15 = 16 raw features PERMUTED by rot=(c>>3)&3;
// word 16+rot = scalar feature. Wr pre-permuted to match -> natural-order
// b128 reads stay perfectly bank-tiled; writes/scalar spread across banks.
// NOTE launch_bounds (256,2): (256,4) made the compiler cap arch-VGPR at 64
// and spill Wr to scratch (round 6: 3.5 GB spill traffic, 10x slowdown).
// (256,2) gives VGPR=128; HW can still co-schedule 4 blocks/CU (LDS 4x40KiB).
template <int NCH>
__launch_bounds__(256, 2)
__global__ void ema_kernel(
    const float* __restrict__ mu_hist, const float* __restrict__ std_hist,
    const float* __restrict__ raw,
    const float* __restrict__ mW, const float* __restrict__ mb, const float* __restrict__ mal,
    const float* __restrict__ sW, const float* __restrict__ sb, const float* __restrict__ sal,
    float* __restrict__ Spart) {
  constexpr int L = Pn / NCH;       // rows per chunk
  constexpr int NPH = L / TBLK;     // phases per chunk
  const int sx = blockIdx.x;        // 0..4*NCH-1
  const int cblk = sx & 1, hblk = (sx >> 1) & 1, ph = sx >> 2;
  const int b = blockIdx.y, br = blockIdx.z;
  const int tid = threadIdx.x;
  const int cr = tid & 31;
  const int w0 = tid >> 5;  // 0..7 : hh-group AND raw w-pair index

  const float* inW = br ? sW : mW;
  const float* inb = br ? sb : mb;
  const float* alog = br ? sal : mal;
  const int hh0 = hblk * 64 + w0 * 8;
  const int rot = (cr >> 3) & 3;

  // Wr[j] = W column for the feature stored at row word j (pre-permuted).
  float Wr[TOKn][8];
#pragma unroll
  for (int j = 0; j < 16; ++j) {
    int feat = 1 + 4 * (((j >> 2) + 4 - rot) & 3) + (j & 3);
    float4 wv0 = *(const float4*)&inW[feat * Hn + hh0];
    float4 wv1 = *(const float4*)&inW[feat * Hn + hh0 + 4];
    Wr[j][0] = wv0.x; Wr[j][1] = wv0.y; Wr[j][2] = wv0.z; Wr[j][3] = wv0.w;
    Wr[j][4] = wv1.x; Wr[j][5] = wv1.y; Wr[j][6] = wv1.z; Wr[j][7] = wv1.w;
  }
  {
    float4 wv0 = *(const float4*)&inW[hh0];
    float4 wv1 = *(const float4*)&inW[hh0 + 4];
    Wr[16][0] = wv0.x; Wr[16][1] = wv0.y; Wr[16][2] = wv0.z; Wr[16][3] = wv0.w;
    Wr[16][4] = wv1.x; Wr[16][5] = wv1.y; Wr[16][6] = wv1.z; Wr[16][7] = wv1.w;
  }
  float av[8], bias[8], h[8];
#pragma unroll
  for (int i = 0; i < 8; ++i) {
    av[i] = 1.0f / (1.0f + expf(-alog[hh0 + i]));
    bias[i] = inb[hh0 + i];
    h[i] = 0.0f;
  }

  const int cs = cblk * 32 + cr;
  const size_t bP = (size_t)b * Pn;
  const float* rawb = raw + bP * Wn * Cn;
  const float* mub = mu_hist + bP * Cn;
  const float* stdb = std_hist + bP * Cn;

  __shared__ float tok[2][TBLK][32 * 20];

  // write offsets for this thread's two raw features (g=w0 and g=w0+8)
  const int wf1 = cr * 20 + 4 * (((w0 >> 2) + rot) & 3) + (w0 & 3);
  const int wf2 = cr * 20 + 4 * ((((w0 + 8) >> 2) + rot) & 3) + (w0 & 3);
  // scalar-feature stager: all 256 threads cover TBLK x 32c
  const int cmu = tid & 31;
  const int tqmu = tid >> 5;  // 0..7
  const int wq_s = cmu * 20 + 16 + ((cmu >> 3) & 3);
  const int cmug = cblk * 32 + cmu;
  const int qo = cr * 20 + 16 + rot;

  const int t0 = ph * L;

  auto STAGE = [&](int tb, int buf) {
#pragma unroll
    for (int tq = 0; tq < TBLK; ++tq) {
      int t = tb + tq;
      const float* rawt = rawb + (size_t)t * (Wn * Cn);
      float r0 = rawt[w0 * Cn + cs];
      float r1 = rawt[(w0 + 8) * Cn + cs];
      if (br == 0) {
        tok[buf][tq][wf1] = r0;
        tok[buf][tq][wf2] = r1;
      } else {
        float mu = mub[(size_t)t * Cn + cs];
        float sd = stdb[(size_t)t * Cn + cs];
        float inv = 1.0f / (sd + 1e-5f);
        tok[buf][tq][wf1] = (r0 - mu) * inv;
        tok[buf][tq][wf2] = (r1 - mu) * inv;
      }
    }
    {
      int t = tb + tqmu;
      float v = br ? logf(fmaxf(stdb[(size_t)t * Cn + cmug], 1e-3f))
                   : mub[(size_t)t * Cn + cmug];
      tok[buf][tqmu][wq_s] = v;
    }
  };

  auto COMPUTE = [&](int buf) {
#pragma unroll
    for (int tq = 0; tq < TBLK; ++tq) {
      const float* row = &tok[buf][tq][cr * 20];
      float4 q0 = *(const float4*)(row);
      float4 q1 = *(const float4*)(row + 4);
      float4 q2 = *(const float4*)(row + 8);
      float4 q3 = *(const float4*)(row + 12);
      float q4 = tok[buf][tq][qo];
#pragma unroll
      for (int i = 0; i < 8; ++i) {
        float u = bias[i];
        u = fmaf(q0.x, Wr[0][i], u);
        u = fmaf(q0.y, Wr[1][i], u);
        u = fmaf(q0.z, Wr[2][i], u);
        u = fmaf(q0.w, Wr[3][i], u);
        u = fmaf(q1.x, Wr[4][i], u);
        u = fmaf(q1.y, Wr[5][i], u);
        u = fmaf(q1.z, Wr[6][i], u);
        u = fmaf(q1.w, Wr[7][i], u);
        u = fmaf(q2.x, Wr[8][i], u);
        u = fmaf(q2.y, Wr[9][i], u);
        u = fmaf(q2.z, Wr[10][i], u);
        u = fmaf(q2.w, Wr[11][i], u);
        u = fmaf(q3.x, Wr[12][i], u);
        u = fmaf(q3.y, Wr[13][i], u);
        u = fmaf(q3.z, Wr[14][i], u);
        u = fmaf(q3.w, Wr[15][i], u);
        u = fmaf(q4, Wr[16][i], u);
        h[i] = fmaf(av[i], h[i] - u, u);  // a*h + (1-a)*u
      }
    }
  };

  STAGE(t0, 0);
  __syncthreads();
  int cur = 0;
#pragma unroll 1
  for (int p = 0; p < NPH; ++p) {
    if (p + 1 < NPH) STAGE(t0 + (p + 1) * TBLK, cur ^ 1);
    COMPUTE(cur);
    __syncthreads();
    cur ^= 1;
  }

  // write chunk-EMA result (uncorrected), thread-contiguous
  const int idx_block = (((br * NCH + ph) * Bn + b) * 2 + cblk) * 2 + hblk;
  float* op = Spart + (size_t)idx_block * 2048 + tid * 8;
  float4 o0 = {h[0], h[1], h[2], h[3]};
  float4 o1 = {h[4], h[5], h[6], h[7]};
  *(float4*)op = o0;
  *(float4*)(op + 4) = o1;
}

// ---------------- Kernel C: combine chunks + centering correction + GELU-MLP head ----------------
// G (b,c) rows per block; NCH chunk composition h = sum_k aL^(NCH-1-k) * h_k.
template <int G, int NCH>
__launch_bounds__(128, 4)
__global__ void head_kernel(
    const float* __restrict__ anchor, const float* __restrict__ lsa,
    const float* __restrict__ mW, const float* __restrict__ sW,
    const float* __restrict__ mal, const float* __restrict__ mpW, const float* __restrict__ mpb,
    const float* __restrict__ moW, const float* __restrict__ mob, const float* __restrict__ gmu,
    const float* __restrict__ sal, const float* __restrict__ spW, const float* __restrict__ spb,
    const float* __restrict__ soW, const float* __restrict__ sob, const float* __restrict__ gst,
    const float* __restrict__ Spart, float* __restrict__ out) {
  constexpr int L = Pn / NCH;
  const int br = blockIdx.y;
  const int bc0 = blockIdx.x * G;  // G (b,c) rows per block
  const int tid = threadIdx.x;     // 0..127 = hh
  const float* alog = br ? sal : mal;
  const float* pW = br ? spW : mpW;
  const float* pb = br ? spb : mpb;
  const float* oW = br ? soW : moW;
  const float* ob = br ? sob : mob;

  __shared__ float smem[2 * G * 128];  // [0,G*128): gelu then reduce; [G*128,..): h2
  float* g_lds = smem;
  float* h2 = smem + G * 128;

  const float a = 1.0f / (1.0f + expf(-alog[tid]));
  float aL = a;  // a^L via log2(L) squarings
#pragma unroll
  for (int s7 = 0; s7 < 31 - __builtin_clz(L); ++s7) aL *= aL;
  float fac[NCH];
  fac[NCH - 1] = 1.0f;
#pragma unroll
  for (int k = NCH - 2; k >= 0; --k) fac[k] = fac[k + 1] * aL;
  const float apF = fac[0] * aL;  // a^Pn
  // centering correction: sum over shifted features of in_W column
  float SWv;
  if (br == 0) {
    float s = 0.f;
#pragma unroll
    for (int k = 0; k < TOKn; ++k) s += mW[k * Hn + tid];
    SWv = s;
  } else {
    SWv = sW[tid];  // only feature 0 (logstd) is shifted
  }
  const float cS = (1.0f - apF) * SWv;

  const int hblk = tid >> 6;
  const int hhg = (tid >> 3) & 7;
  const int ii = tid & 7;

  float hreg[G];
#pragma unroll
  for (int g = 0; g < G; ++g) {
    int bc = bc0 + g;
    int bb = bc >> 6, cc = bc & 63;
    int cblk2 = cc >> 5, crr = cc & 31;
    const size_t inner = (size_t)(hhg * 32 + crr) * 8 + ii;
    const int blk0 = (((br * NCH + 0) * Bn + bb) * 2 + cblk2) * 2 + hblk;
    float hv = 0.f;
#pragma unroll
    for (int k = 0; k < NCH; ++k) {
      hv = fmaf(fac[k], Spart[(size_t)(blk0 + k * (Bn * 4)) * 2048 + inner], hv);
    }
    float shiftv = br ? lsa[bb * Cn + cc] : anchor[bb * Cn + cc];
    hv = fmaf(-cS, shiftv, hv);  // centering correction
    hreg[g] = hv;
    g_lds[g * 128 + tid] = 0.5f * hv * (1.0f + erff(hv * 0.70710678118654752f));
  }
  __syncthreads();

  float acc[G];
#pragma unroll
  for (int g = 0; g < G; ++g) acc[g] = hreg[g] + pb[tid];
  for (int j = 0; j < 128; j += 4) {
    float w0v = pW[j * Hn + tid];
    float w1v = pW[(j + 1) * Hn + tid];
    float w2v = pW[(j + 2) * Hn + tid];
    float w3v = pW[(j + 3) * Hn + tid];
#pragma unroll
    for (int g = 0; g < G; ++g) {
      float4 gv = *(const float4*)&g_lds[g * 128 + j];
      acc[g] = fmaf(gv.x, w0v, acc[g]);
      acc[g] = fmaf(gv.y, w1v, acc[g]);
      acc[g] = fmaf(gv.z, w2v, acc[g]);
      acc[g] = fmaf(gv.w, w3v, acc[g]);
    }
  }
#pragma unroll
  for (int g = 0; g < G; ++g) h2[g * 128 + tid] = acc[g];
  __syncthreads();

  // out projection: p = tid&63, j-half = tid>>6
  const int p = tid & 63;
  const int jh = tid >> 6;
  float s[G];
#pragma unroll
  for (int g = 0; g < G; ++g) s[g] = 0.f;
  for (int jj = 0; jj < 64; jj += 4) {
    int j = jh * 64 + jj;
    float w0v = oW[j * PREDn + p];
    float w1v = oW[(j + 1) * PREDn + p];
    float w2v = oW[(j + 2) * PREDn + p];
    float w3v = oW[(j + 3) * PREDn + p];
#pragma unroll
    for (int g = 0; g < G; ++g) {
      float4 hv4 = *(const float4*)&h2[g * 128 + j];
      s[g] = fmaf(hv4.x, w0v, s[g]);
      s[g] = fmaf(hv4.y, w1v, s[g]);
      s[g] = fmaf(hv4.z, w2v, s[g]);
      s[g] = fmaf(hv4.w, w3v, s[g]);
    }
  }
  float* red = smem;  // reuse g_lds region (no longer read)
#pragma unroll
  for (int g = 0; g < G; ++g) red[jh * (G * 64) + g * 64 + p] = s[g];
  __syncthreads();
  if (tid < 64) {
#pragma unroll
    for (int g = 0; g < G; ++g) {
      int bc = bc0 + g;
      int bb = bc >> 6, cc = bc & 63;
      float tot = red[g * 64 + p] + red[G * 64 + g * 64 + p] + ob[p];
      if (br == 0) {
        out[((size_t)bb * PREDn + p) * Cn + cc] = fmaf(gmu[cc], tot, anchor[bb * Cn + cc]);
      } else {
        float lf = fmaf(gst[cc], tot, lsa[bb * Cn + cc]);
        out[131072 + ((size_t)bb * PREDn + p) * Cn + cc] = fmaxf(expf(lf), 1e-3f);
      }
    }
  }
}

extern "C" void kernel_launch(void* const* d_in, const int* in_sizes, int n_in,
                              void* d_out, int out_size, void* d_ws, size_t ws_size,
                              hipStream_t stream) {
  (void)in_sizes; (void)n_in; (void)out_size;
  const float* mu_hist = (const float*)d_in[0];
  const float* std_hist = (const float*)d_in[1];
  const float* anchor = (const float*)d_in[2];
  const float* raw = (const float*)d_in[3];
  const float* mW = (const float*)d_in[4];
  const float* mb_ = (const float*)d_in[5];
  const float* mal = (const float*)d_in[6];
  const float* mpW = (const float*)d_in[7];
  const float* mpb = (const float*)d_in[8];
  const float* moW = (const float*)d_in[9];
  const float* mob = (const float*)d_in[10];
  const float* gmu = (const float*)d_in[11];
  const float* sW = (const float*)d_in[12];
  const float* sb_ = (const float*)d_in[13];
  const float* sal = (const float*)d_in[14];
  const float* spW = (const float*)d_in[15];
  const float* spb = (const float*)d_in[16];
  const float* soW = (const float*)d_in[17];
  const float* sob = (const float*)d_in[18];
  const float* gst = (const float*)d_in[19];
  float* out = (float*)d_out;
  float* ws = (float*)d_ws;

  float* lsa = ws;                  // 2048 floats
  float* lsa_part = ws + 2048;      // 8*2048 floats
  float* Spart = ws + 2048 + 16384; // up to 1024*2048 floats (NCH=4)

  const size_t need4 = (size_t)(2048 + 16384 + 1024 * 2048) * 4;

  hipLaunchKernelGGL(lsa_part_kernel, dim3(32, 8), dim3(256), 0, stream, std_hist, lsa_part);
  hipLaunchKernelGGL(lsa_combine_kernel, dim3(8), dim3(256), 0, stream, lsa_part, lsa);
  if (ws_size >= need4) {
    hipLaunchKernelGGL(HIP_KERNEL_NAME(ema_kernel<4>), dim3(16, 32, 2), dim3(256), 0, stream,
                       mu_hist, std_hist, raw, mW, mb_, mal, sW, sb_, sal, Spart);
    hipLaunchKernelGGL(HIP_KERNEL_NAME(head_kernel<2, 4>), dim3(1024, 2), dim3(128), 0, stream,
                       anchor, lsa, mW, sW, mal, mpW, mpb, moW, mob, gmu,
                       sal, spW, spb, soW, sob, gst, Spart, out);
  } else {
    hipLaunchKernelGGL(HIP_KERNEL_NAME(ema_kernel<2>), dim3(8, 32, 2), dim3(256), 0, stream,
                       mu_hist, std_hist, raw, mW, mb_, mal, sW, sb_, sal, Spart);
    hipLaunchKernelGGL(HIP_KERNEL_NAME(head_kernel<2, 2>), dim3(1024, 2), dim3(128), 0, stream,
                       anchor, lsa, mW, sW, mal, mpW, mpb, moW, mob, gmu,
                       sal, spW, spb, soW, sob, gst, Spart, out);
  }
}